// Round 6
// baseline (137.098 us; speedup 1.0000x reference)
//
#include <hip/hip_runtime.h>
#include <math.h>

#define D 256
#define K2 512          // 2*D
#define BATCH 1024      // n2
#define N1 11264        // n1 = B*(1+10)
#define S0 25
#define S1 10
#define NB0 176         // N1/64 gemm0 blocks (= mega grid)
#define NB1 64          // layer1 blocks (BATCH/16)

typedef __bf16 bf16x8 __attribute__((ext_vector_type(8)));
typedef __bf16 bf16x4 __attribute__((ext_vector_type(4)));
typedef float  f32x4  __attribute__((ext_vector_type(4)));

// ---------------------------------------------------------------------------
// prep: convert W0/W1 to bf16 (first 65536 threads), zero the barrier counter,
// and build X0[N1][512] (bf16) = [feat[nodes1[i]] | mean_j feat[neigh1[i][j]]].
// One wave per node; lane l owns dims [4l,4l+4). (R3-measured: 59.4us)
// ---------------------------------------------------------------------------
__global__ __launch_bounds__(256) void prep_kernel(
        const float* __restrict__ feat, const float* __restrict__ W0,
        const float* __restrict__ W1, const int* __restrict__ nodes2,
        const int* __restrict__ neigh2, const int* __restrict__ neigh1,
        __bf16* __restrict__ Wb0, __bf16* __restrict__ Wb1,
        __bf16* __restrict__ X0, unsigned int* __restrict__ ctr) {
    const int gtid = blockIdx.x * 256 + threadIdx.x;
    if (gtid == 0) *ctr = 0;   // barrier counter for mega kernel (flushed at kernel end)
    if (gtid < 65536) {
        const float* src = (gtid < 32768) ? W0 : W1;
        __bf16* dst = (gtid < 32768) ? Wb0 : Wb1;
        const int i = gtid & 32767;
        float4 v = ((const float4*)src)[i];
        bf16x4 o = { (__bf16)v.x, (__bf16)v.y, (__bf16)v.z, (__bf16)v.w };
        *(bf16x4*)(dst + (size_t)i * 4) = o;
    }
    const int wave = gtid >> 6;
    const int lane = threadIdx.x & 63;
    if (wave >= N1) return;
    const int self_idx = (wave < BATCH) ? nodes2[wave] : neigh2[wave - BATCH];
    float4 selfv = ((const float4*)(feat + (size_t)self_idx * D))[lane];
    float4 acc = make_float4(0.f, 0.f, 0.f, 0.f);
    const int* nb = neigh1 + (size_t)wave * S0;
#pragma unroll
    for (int j = 0; j < S0; ++j) {
        int idx = nb[j];
        float4 v = ((const float4*)(feat + (size_t)idx * D))[lane];
        acc.x += v.x; acc.y += v.y; acc.z += v.z; acc.w += v.w;
    }
    const float s = 1.0f / (float)S0;
    bf16x4 sv = { (__bf16)selfv.x, (__bf16)selfv.y, (__bf16)selfv.z, (__bf16)selfv.w };
    bf16x4 av = { (__bf16)(acc.x * s), (__bf16)(acc.y * s),
                  (__bf16)(acc.z * s), (__bf16)(acc.w * s) };
    __bf16* xrow = X0 + (size_t)wave * K2;
    *(bf16x4*)(xrow + lane * 4) = sv;         // dims [0,256)
    *(bf16x4*)(xrow + 256 + lane * 4) = av;   // dims [256,512)
}

// ---------------------------------------------------------------------------
// mega: phase 1 = gemm0 (RB=64, all 176 blocks):
//         h1b = l2norm(relu(X0 @ W0^T + b0))   (bf16)
//       device-scope spin barrier (all 176 blocks co-resident: 176<=256 CUs,
//         LDS ~41KB -> >=2 blocks/CU; counter pre-zeroed by prep)
//       phase 2 = layer1 (blocks 0..63, 16 rows each):
//         out = l2norm(relu([h1|mean10(h1)] @ W1^T + b1))  (fp32)
// LDS tile16 layout: slot i -> group i>>7, k-chunk (i>>4)&7, low i&15; wave
// fragment reads span contiguous 1KB -> conflict-free; staging writes linear.
// Fragment mapping (m89): A/B lane l: row/col=l&15, k=(l>>4)*8+i.
// C/D: col=l&15, row=(l>>4)*4+reg.
// ---------------------------------------------------------------------------
__global__ __launch_bounds__(256, 2) void mega_kernel(
        const __bf16* __restrict__ X0, const __bf16* __restrict__ Wb0,
        const float* __restrict__ b0, const __bf16* __restrict__ Wb1,
        const float* __restrict__ b1, __bf16* __restrict__ h1b,
        float* __restrict__ out, unsigned int* __restrict__ ctr) {
    __shared__ __bf16 As[64 * 64];       // 8KB (phase 2 reuses first 2KB)
    __shared__ __bf16 Bs[256 * 64];      // 32KB
    __shared__ float ssLDS[4][64];
    __shared__ float invLDS[64];

    const int tid = threadIdx.x;
    const int lane = tid & 63;
    const int w = tid >> 6;
    const int rl = lane & 15;
    const int g = lane >> 4;

    // ================= phase 1: gemm0, RB=64 =================
    {
        constexpr int RF = 4;           // 64/16
        constexpr int NA = 512;         // 64 rows * 8 granules
        const int row0 = blockIdx.x * 64;

        uint4 ra[2], rb[8];
#pragma unroll
        for (int s = 0; s < 2; ++s) {
            int i = tid + s * 256;
            int rg = i >> 7, kc = (i >> 4) & 7, lo = i & 15;
            ra[s] = *(const uint4*)(X0 + (size_t)(row0 + rg * 16 + lo) * K2 + kc * 8);
        }
#pragma unroll
        for (int s = 0; s < 8; ++s) {
            int i = tid + s * 256;
            int cg = i >> 7, kc = (i >> 4) & 7, lo = i & 15;
            rb[s] = *(const uint4*)(Wb0 + (size_t)(cg * 16 + lo) * K2 + kc * 8);
        }

        f32x4 acc[RF][4];
#pragma unroll
        for (int rf = 0; rf < RF; ++rf)
#pragma unroll
            for (int nf = 0; nf < 4; ++nf) acc[rf][nf] = (f32x4){0.f, 0.f, 0.f, 0.f};

        for (int k0 = 0; k0 < K2; k0 += 64) {
#pragma unroll
            for (int s = 0; s < 2; ++s)
                *(uint4*)(As + (size_t)(tid + s * 256) * 8) = ra[s];
#pragma unroll
            for (int s = 0; s < 8; ++s)
                *(uint4*)(Bs + (size_t)(tid + s * 256) * 8) = rb[s];
            __syncthreads();
            if (k0 + 64 < K2) {
                int kn = k0 + 64;
#pragma unroll
                for (int s = 0; s < 2; ++s) {
                    int i = tid + s * 256;
                    int rg = i >> 7, kc = (i >> 4) & 7, lo = i & 15;
                    ra[s] = *(const uint4*)(X0 + (size_t)(row0 + rg * 16 + lo) * K2 + kn + kc * 8);
                }
#pragma unroll
                for (int s = 0; s < 8; ++s) {
                    int i = tid + s * 256;
                    int cg = i >> 7, kc = (i >> 4) & 7, lo = i & 15;
                    rb[s] = *(const uint4*)(Wb0 + (size_t)(cg * 16 + lo) * K2 + kn + kc * 8);
                }
            }
#pragma unroll
            for (int kf = 0; kf < 2; ++kf) {
                const int kc = kf * 4 + g;
                bf16x8 af[RF], bfr[4];
#pragma unroll
                for (int rf = 0; rf < RF; ++rf)
                    af[rf] = *(const bf16x8*)(As + ((size_t)(rf * 8 + kc) * 16 + rl) * 8);
#pragma unroll
                for (int nf = 0; nf < 4; ++nf)
                    bfr[nf] = *(const bf16x8*)(Bs + ((size_t)((w * 4 + nf) * 8 + kc) * 16 + rl) * 8);
#pragma unroll
                for (int rf = 0; rf < RF; ++rf)
#pragma unroll
                    for (int nf = 0; nf < 4; ++nf)
                        acc[rf][nf] = __builtin_amdgcn_mfma_f32_16x16x32_bf16(
                            af[rf], bfr[nf], acc[rf][nf], 0, 0, 0);
            }
            __syncthreads();
        }

        float bv[4];
#pragma unroll
        for (int nf = 0; nf < 4; ++nf) bv[nf] = b0[w * 64 + nf * 16 + rl];

#pragma unroll
        for (int rf = 0; rf < RF; ++rf) {
            float ss0 = 0.f, ss1 = 0.f, ss2 = 0.f, ss3 = 0.f;
#pragma unroll
            for (int nf = 0; nf < 4; ++nf) {
                float v0 = fmaxf(acc[rf][nf][0] + bv[nf], 0.f);
                float v1 = fmaxf(acc[rf][nf][1] + bv[nf], 0.f);
                float v2 = fmaxf(acc[rf][nf][2] + bv[nf], 0.f);
                float v3 = fmaxf(acc[rf][nf][3] + bv[nf], 0.f);
                acc[rf][nf][0] = v0; acc[rf][nf][1] = v1;
                acc[rf][nf][2] = v2; acc[rf][nf][3] = v3;
                ss0 += v0 * v0; ss1 += v1 * v1; ss2 += v2 * v2; ss3 += v3 * v3;
            }
#pragma unroll
            for (int m = 1; m < 16; m <<= 1) {
                ss0 += __shfl_xor(ss0, m);
                ss1 += __shfl_xor(ss1, m);
                ss2 += __shfl_xor(ss2, m);
                ss3 += __shfl_xor(ss3, m);
            }
            float ssv = (rl == 0) ? ss0 : (rl == 1) ? ss1 : (rl == 2) ? ss2 : ss3;
            if (rl < 4) ssLDS[w][rf * 16 + g * 4 + rl] = ssv;
        }
        __syncthreads();
        if (tid < 64) {
            float t = ssLDS[0][tid] + ssLDS[1][tid] + ssLDS[2][tid] + ssLDS[3][tid];
            invLDS[tid] = (t > 0.f) ? rsqrtf(t) : 1.0f;
        }
        __syncthreads();
#pragma unroll
        for (int rf = 0; rf < RF; ++rf)
#pragma unroll
            for (int j = 0; j < 4; ++j) {
                const int row = rf * 16 + g * 4 + j;
                const float inv = invLDS[row];
#pragma unroll
                for (int nf = 0; nf < 4; ++nf)
                    h1b[(size_t)(row0 + row) * D + w * 64 + nf * 16 + rl] =
                        (__bf16)(acc[rf][nf][j] * inv);
            }
    }

    // ================= device-scope barrier =================
    __syncthreads();
    __threadfence();                      // release h1b stores (agent scope)
    if (tid == 0) {
        __hip_atomic_fetch_add(ctr, 1u, __ATOMIC_ACQ_REL, __HIP_MEMORY_SCOPE_AGENT);
        while (__hip_atomic_load(ctr, __ATOMIC_ACQUIRE, __HIP_MEMORY_SCOPE_AGENT) < NB0)
            __builtin_amdgcn_s_sleep(2);
    }
    __syncthreads();
    if (blockIdx.x >= NB1) return;

    // ================= phase 2: layer1, 16 rows/block =================
    {
        const int rows0 = blockIdx.x * 16;

        f32x4 acc[4];
#pragma unroll
        for (int nf = 0; nf < 4; ++nf) acc[nf] = (f32x4){0.f, 0.f, 0.f, 0.f};

        for (int k0 = 0; k0 < K2; k0 += 64) {
            // A-staging: threads 0..127; slot = kc8*16 + r (matches fragment reads)
            if (tid < 128) {
                const int r = tid >> 3, kc8 = tid & 7;
                const int grow = rows0 + r;
                bf16x8 av;
                if (k0 < 256) {
                    av = *(const bf16x8*)(h1b + (size_t)grow * D + k0 + kc8 * 8);
                } else {
                    const __bf16* base = h1b + (size_t)(BATCH + grow * S1) * D + (k0 - 256) + kc8 * 8;
                    bf16x8 vr[S1];
#pragma unroll
                    for (int j = 0; j < S1; ++j)
                        vr[j] = *(const bf16x8*)(base + (size_t)j * D);
                    float f[8];
#pragma unroll
                    for (int e = 0; e < 8; ++e) f[e] = 0.f;
#pragma unroll
                    for (int j = 0; j < S1; ++j)
#pragma unroll
                        for (int e = 0; e < 8; ++e) f[e] += (float)vr[j][e];
#pragma unroll
                    for (int e = 0; e < 8; ++e) av[e] = (__bf16)(f[e] * 0.1f);
                }
                *(bf16x8*)(As + (size_t)(kc8 * 16 + r) * 8) = av;
            }
            // B-staging
#pragma unroll
            for (int s = 0; s < 8; ++s) {
                int i = tid + s * 256;
                int cg = i >> 7, kc = (i >> 4) & 7, lo = i & 15;
                *(uint4*)(Bs + (size_t)i * 8) =
                    *(const uint4*)(Wb1 + (size_t)(cg * 16 + lo) * K2 + k0 + kc * 8);
            }
            __syncthreads();
#pragma unroll
            for (int kf = 0; kf < 2; ++kf) {
                const int kc = kf * 4 + g;
                bf16x8 af = *(const bf16x8*)(As + ((size_t)kc * 16 + rl) * 8);
                bf16x8 bfr[4];
#pragma unroll
                for (int nf = 0; nf < 4; ++nf)
                    bfr[nf] = *(const bf16x8*)(Bs + ((size_t)((w * 4 + nf) * 8 + kc) * 16 + rl) * 8);
#pragma unroll
                for (int nf = 0; nf < 4; ++nf)
                    acc[nf] = __builtin_amdgcn_mfma_f32_16x16x32_bf16(
                        af, bfr[nf], acc[nf], 0, 0, 0);
            }
            __syncthreads();
        }

        float bv[4];
#pragma unroll
        for (int nf = 0; nf < 4; ++nf) bv[nf] = b1[w * 64 + nf * 16 + rl];

        float ss0 = 0.f, ss1 = 0.f, ss2 = 0.f, ss3 = 0.f;
#pragma unroll
        for (int nf = 0; nf < 4; ++nf) {
            float v0 = fmaxf(acc[nf][0] + bv[nf], 0.f);
            float v1 = fmaxf(acc[nf][1] + bv[nf], 0.f);
            float v2 = fmaxf(acc[nf][2] + bv[nf], 0.f);
            float v3 = fmaxf(acc[nf][3] + bv[nf], 0.f);
            acc[nf][0] = v0; acc[nf][1] = v1;
            acc[nf][2] = v2; acc[nf][3] = v3;
            ss0 += v0 * v0; ss1 += v1 * v1; ss2 += v2 * v2; ss3 += v3 * v3;
        }
#pragma unroll
        for (int m = 1; m < 16; m <<= 1) {
            ss0 += __shfl_xor(ss0, m);
            ss1 += __shfl_xor(ss1, m);
            ss2 += __shfl_xor(ss2, m);
            ss3 += __shfl_xor(ss3, m);
        }
        float ssv = (rl == 0) ? ss0 : (rl == 1) ? ss1 : (rl == 2) ? ss2 : ss3;
        if (rl < 4) ssLDS[w][g * 4 + rl] = ssv;
        __syncthreads();
        if (tid < 16) {
            float t = ssLDS[0][tid] + ssLDS[1][tid] + ssLDS[2][tid] + ssLDS[3][tid];
            invLDS[tid] = (t > 0.f) ? rsqrtf(t) : 1.0f;
        }
        __syncthreads();
#pragma unroll
        for (int j = 0; j < 4; ++j) {
            const int row = g * 4 + j;
            const float inv = invLDS[row];
#pragma unroll
            for (int nf = 0; nf < 4; ++nf)
                out[(size_t)(rows0 + row) * D + w * 64 + nf * 16 + rl] = acc[nf][j] * inv;
        }
    }
}

// ---------------------------------------------------------------------------
extern "C" void kernel_launch(void* const* d_in, const int* in_sizes, int n_in,
                              void* d_out, int out_size, void* d_ws, size_t ws_size,
                              hipStream_t stream) {
    const float* features = (const float*)d_in[0];
    const float* W0       = (const float*)d_in[1];
    const float* b0       = (const float*)d_in[2];
    const float* W1       = (const float*)d_in[3];
    const float* b1       = (const float*)d_in[4];
    const int*   nodes2   = (const int*)d_in[5];
    const int*   neigh2   = (const int*)d_in[6];
    const int*   neigh1   = (const int*)d_in[7];
    float* out = (float*)d_out;

    // workspace layout
    char* ws = (char*)d_ws;
    __bf16* Wb0 = (__bf16*)ws;                               // 256 KB
    __bf16* Wb1 = (__bf16*)(ws + 262144);                    // 256 KB
    __bf16* X0b = (__bf16*)(ws + 524288);                    // 11264*512*2 = 11.5 MB
    __bf16* h1b = (__bf16*)(ws + 524288 + 11534336);         // 11264*256*2 = 5.75 MB
    unsigned int* ctr = (unsigned int*)(ws + 524288 + 11534336 + 5767168);

    prep_kernel<<<N1 / 4, 256, 0, stream>>>(features, W0, W1, nodes2, neigh2,
                                            neigh1, Wb0, Wb1, X0b, ctr);
    mega_kernel<<<NB0, 256, 0, stream>>>(X0b, Wb0, b0, Wb1, b1, h1b, out, ctr);
}

// Round 7
// 120.363 us; speedup vs baseline: 1.1390x; 1.1390x over previous
//
#include <hip/hip_runtime.h>
#include <math.h>

#define D 256
#define K2 512          // 2*D
#define BATCH 1024      // n2
#define N1 11264        // n1 = B*(1+10)
#define S0 25
#define S1 10

typedef __bf16 bf16x8 __attribute__((ext_vector_type(8)));
typedef __bf16 bf16x4 __attribute__((ext_vector_type(4)));
typedef float  f32x4  __attribute__((ext_vector_type(4)));

// ---------------------------------------------------------------------------
// prep: convert W0/W1 to bf16 (first 65536 threads) and build X0[N1][512]
// (bf16) = [feat[nodes1[i]] | mean_j feat[neigh1[i][j]]]. One wave per node;
// lane l owns dims [4l,4l+4). Measured 59.4us (R3) - near random-gather ceiling.
// ---------------------------------------------------------------------------
__global__ __launch_bounds__(256) void prep_kernel(
        const float* __restrict__ feat, const float* __restrict__ W0,
        const float* __restrict__ W1, const int* __restrict__ nodes2,
        const int* __restrict__ neigh2, const int* __restrict__ neigh1,
        __bf16* __restrict__ Wb0, __bf16* __restrict__ Wb1,
        __bf16* __restrict__ X0) {
    const int gtid = blockIdx.x * 256 + threadIdx.x;
    if (gtid < 65536) {
        const float* src = (gtid < 32768) ? W0 : W1;
        __bf16* dst = (gtid < 32768) ? Wb0 : Wb1;
        const int i = gtid & 32767;
        float4 v = ((const float4*)src)[i];
        bf16x4 o = { (__bf16)v.x, (__bf16)v.y, (__bf16)v.z, (__bf16)v.w };
        *(bf16x4*)(dst + (size_t)i * 4) = o;
    }
    const int wave = gtid >> 6;
    const int lane = threadIdx.x & 63;
    if (wave >= N1) return;
    const int self_idx = (wave < BATCH) ? nodes2[wave] : neigh2[wave - BATCH];
    float4 selfv = ((const float4*)(feat + (size_t)self_idx * D))[lane];
    float4 acc = make_float4(0.f, 0.f, 0.f, 0.f);
    const int* nb = neigh1 + (size_t)wave * S0;
#pragma unroll
    for (int j = 0; j < S0; ++j) {
        int idx = nb[j];
        float4 v = ((const float4*)(feat + (size_t)idx * D))[lane];
        acc.x += v.x; acc.y += v.y; acc.z += v.z; acc.w += v.w;
    }
    const float s = 1.0f / (float)S0;
    bf16x4 sv = { (__bf16)selfv.x, (__bf16)selfv.y, (__bf16)selfv.z, (__bf16)selfv.w };
    bf16x4 av = { (__bf16)(acc.x * s), (__bf16)(acc.y * s),
                  (__bf16)(acc.z * s), (__bf16)(acc.w * s) };
    __bf16* xrow = X0 + (size_t)wave * K2;
    *(bf16x4*)(xrow + lane * 4) = sv;         // dims [0,256)
    *(bf16x4*)(xrow + 256 + lane * 4) = av;   // dims [256,512)
}

// ---------------------------------------------------------------------------
// gemm0: h1b[N1][256] = l2norm_rows(relu(X0 @ W0^T + b0)), bf16 out.
// 512 threads = 8 waves: wave (wr,wc) = (w>>2, w&3); wr owns 16-row group,
// wc owns cols [64wc,64wc+64). RB=32 -> grid 352 -> ~11 waves/CU (high TLP).
// tile16 LDS: slot i -> group i>>7, kc=(i>>4)&7, lo=i&15; fragment reads span
// contiguous 1KB (conflict-free, m136); staging writes LDS-linear.
// Fragment map (m89): A/B lane l: row/col=l&15, k=(l>>4)*8+i. C/D: col=l&15,
// row=(l>>4)*4+reg.
// ---------------------------------------------------------------------------
__global__ __launch_bounds__(512, 2) void gemm0_kernel(
        const __bf16* __restrict__ X0, const __bf16* __restrict__ Wb0,
        const float* __restrict__ b0, __bf16* __restrict__ h1b) {
    __shared__ __bf16 As[32 * 64];    // 4KB
    __shared__ __bf16 Bs[256 * 64];   // 32KB
    __shared__ float ssLDS[4][32];
    __shared__ float invLDS[32];

    const int tid = threadIdx.x;
    const int lane = tid & 63;
    const int w = tid >> 6;
    const int wr = w >> 2;            // row-group 0..1
    const int wc = w & 3;             // col-group 0..3
    const int rl = lane & 15;
    const int g = lane >> 4;
    const int row0 = blockIdx.x * 32;

    // prologue loads (k0 = 0)
    uint4 ra;
    const bool hasA = tid < 256;
    if (hasA) {
        int rg = tid >> 7, kc = (tid >> 4) & 7, lo = tid & 15;
        ra = *(const uint4*)(X0 + (size_t)(row0 + rg * 16 + lo) * K2 + kc * 8);
    }
    uint4 rb[4];
#pragma unroll
    for (int s = 0; s < 4; ++s) {
        int i = tid + s * 512;
        int cg = i >> 7, kc = (i >> 4) & 7, lo = i & 15;
        rb[s] = *(const uint4*)(Wb0 + (size_t)(cg * 16 + lo) * K2 + kc * 8);
    }

    f32x4 acc[4];
#pragma unroll
    for (int nf = 0; nf < 4; ++nf) acc[nf] = (f32x4){0.f, 0.f, 0.f, 0.f};

    for (int k0 = 0; k0 < K2; k0 += 64) {
        if (hasA) *(uint4*)(As + (size_t)tid * 8) = ra;
#pragma unroll
        for (int s = 0; s < 4; ++s)
            *(uint4*)(Bs + (size_t)(tid + s * 512) * 8) = rb[s];
        __syncthreads();
        if (k0 + 64 < K2) {
            const int kn = k0 + 64;
            if (hasA) {
                int rg = tid >> 7, kc = (tid >> 4) & 7, lo = tid & 15;
                ra = *(const uint4*)(X0 + (size_t)(row0 + rg * 16 + lo) * K2 + kn + kc * 8);
            }
#pragma unroll
            for (int s = 0; s < 4; ++s) {
                int i = tid + s * 512;
                int cg = i >> 7, kc = (i >> 4) & 7, lo = i & 15;
                rb[s] = *(const uint4*)(Wb0 + (size_t)(cg * 16 + lo) * K2 + kn + kc * 8);
            }
        }
#pragma unroll
        for (int kf = 0; kf < 2; ++kf) {
            const int kc = kf * 4 + g;
            bf16x8 af = *(const bf16x8*)(As + ((size_t)(wr * 8 + kc) * 16 + rl) * 8);
            bf16x8 bfr[4];
#pragma unroll
            for (int nf = 0; nf < 4; ++nf)
                bfr[nf] = *(const bf16x8*)(Bs + ((size_t)((wc * 4 + nf) * 8 + kc) * 16 + rl) * 8);
#pragma unroll
            for (int nf = 0; nf < 4; ++nf)
                acc[nf] = __builtin_amdgcn_mfma_f32_16x16x32_bf16(af, bfr[nf], acc[nf], 0, 0, 0);
        }
        __syncthreads();
    }

    // epilogue: bias + relu + row L2 norm (cross-wc via LDS) + store bf16
    float bv[4];
#pragma unroll
    for (int nf = 0; nf < 4; ++nf) bv[nf] = b0[wc * 64 + nf * 16 + rl];

    float ss0 = 0.f, ss1 = 0.f, ss2 = 0.f, ss3 = 0.f;
#pragma unroll
    for (int nf = 0; nf < 4; ++nf) {
        float v0 = fmaxf(acc[nf][0] + bv[nf], 0.f);
        float v1 = fmaxf(acc[nf][1] + bv[nf], 0.f);
        float v2 = fmaxf(acc[nf][2] + bv[nf], 0.f);
        float v3 = fmaxf(acc[nf][3] + bv[nf], 0.f);
        acc[nf][0] = v0; acc[nf][1] = v1;
        acc[nf][2] = v2; acc[nf][3] = v3;
        ss0 += v0 * v0; ss1 += v1 * v1; ss2 += v2 * v2; ss3 += v3 * v3;
    }
#pragma unroll
    for (int m = 1; m < 16; m <<= 1) {
        ss0 += __shfl_xor(ss0, m);
        ss1 += __shfl_xor(ss1, m);
        ss2 += __shfl_xor(ss2, m);
        ss3 += __shfl_xor(ss3, m);
    }
    float ssv = (rl == 0) ? ss0 : (rl == 1) ? ss1 : (rl == 2) ? ss2 : ss3;
    if (rl < 4) ssLDS[wc][wr * 16 + g * 4 + rl] = ssv;
    __syncthreads();
    if (tid < 32) {
        float t = ssLDS[0][tid] + ssLDS[1][tid] + ssLDS[2][tid] + ssLDS[3][tid];
        invLDS[tid] = (t > 0.f) ? rsqrtf(t) : 1.0f;
    }
    __syncthreads();
#pragma unroll
    for (int j = 0; j < 4; ++j) {
        const int row = wr * 16 + g * 4 + j;
        const float inv = invLDS[row];
#pragma unroll
        for (int nf = 0; nf < 4; ++nf)
            h1b[(size_t)(row0 + row) * D + wc * 64 + nf * 16 + rl] =
                (__bf16)(acc[nf][j] * inv);
    }
}

// ---------------------------------------------------------------------------
// layer1: out[1024][256] = l2norm(relu(X1 @ W1^T + b1)); X1 row i =
// [h1[i] | mean_j h1[1024+i*10+j]], built on the fly. RB=16 -> 64 blocks.
// Both the A rows (incl. the 10 agg loads) and B are reg-prefetched one
// k-tile ahead so the scattered h1 reads hide under MFMA.
// ---------------------------------------------------------------------------
__global__ __launch_bounds__(256, 2) void layer1_kernel(
        const __bf16* __restrict__ h1, const __bf16* __restrict__ Wb1,
        const float* __restrict__ b1, float* __restrict__ out) {
    __shared__ __bf16 As[16 * 64];    // 2KB: slot = kc*16 + r
    __shared__ __bf16 Bs[256 * 64];   // 32KB
    __shared__ float ssLDS[4][16];
    __shared__ float invLDS[16];

    const int tid = threadIdx.x;
    const int lane = tid & 63;
    const int w = tid >> 6;
    const int rl = lane & 15;
    const int g = lane >> 4;
    const int rows0 = blockIdx.x * 16;
    const bool hasA = tid < 128;
    const int r = tid >> 3, kc8 = tid & 7;       // A slot: row r, k-chunk kc8
    const int grow = rows0 + r;

    bf16x8 areg[S1];
    uint4 breg[8];
    int acur = 1;

    // prologue (k0 = 0): self phase
    if (hasA) areg[0] = *(const bf16x8*)(h1 + (size_t)grow * D + kc8 * 8);
#pragma unroll
    for (int s = 0; s < 8; ++s) {
        int i = tid + s * 256;
        int cg = i >> 7, kc = (i >> 4) & 7, blo = i & 15;
        breg[s] = *(const uint4*)(Wb1 + (size_t)(cg * 16 + blo) * K2 + kc * 8);
    }

    f32x4 acc[4];
#pragma unroll
    for (int nf = 0; nf < 4; ++nf) acc[nf] = (f32x4){0.f, 0.f, 0.f, 0.f};

    for (int k0 = 0; k0 < K2; k0 += 64) {
        // write staged A
        if (hasA) {
            bf16x8 av;
            if (acur == 1) {
                av = areg[0];
            } else {
                float f[8];
#pragma unroll
                for (int e = 0; e < 8; ++e) f[e] = 0.f;
#pragma unroll
                for (int j = 0; j < S1; ++j)
#pragma unroll
                    for (int e = 0; e < 8; ++e) f[e] += (float)areg[j][e];
#pragma unroll
                for (int e = 0; e < 8; ++e) av[e] = (__bf16)(f[e] * 0.1f);
            }
            *(bf16x8*)(As + (size_t)(kc8 * 16 + r) * 8) = av;
        }
        // write staged B
#pragma unroll
        for (int s = 0; s < 8; ++s)
            *(uint4*)(Bs + (size_t)(tid + s * 256) * 8) = breg[s];
        __syncthreads();
        // prefetch next k-tile
        if (k0 + 64 < K2) {
            const int kn = k0 + 64;
            if (hasA) {
                if (kn < 256) {
                    areg[0] = *(const bf16x8*)(h1 + (size_t)grow * D + kn + kc8 * 8);
                    acur = 1;
                } else {
                    const __bf16* base = h1 + (size_t)(BATCH + grow * S1) * D + (kn - 256) + kc8 * 8;
#pragma unroll
                    for (int j = 0; j < S1; ++j)
                        areg[j] = *(const bf16x8*)(base + (size_t)j * D);
                    acur = S1;
                }
            }
#pragma unroll
            for (int s = 0; s < 8; ++s) {
                int i = tid + s * 256;
                int cg = i >> 7, kc = (i >> 4) & 7, blo = i & 15;
                breg[s] = *(const uint4*)(Wb1 + (size_t)(cg * 16 + blo) * K2 + kn + kc * 8);
            }
        }
        // MFMA
#pragma unroll
        for (int kf = 0; kf < 2; ++kf) {
            const int kc = kf * 4 + g;
            bf16x8 af = *(const bf16x8*)(As + ((size_t)kc * 16 + rl) * 8);
            bf16x8 bfr[4];
#pragma unroll
            for (int nf = 0; nf < 4; ++nf)
                bfr[nf] = *(const bf16x8*)(Bs + ((size_t)((w * 4 + nf) * 8 + kc) * 16 + rl) * 8);
#pragma unroll
            for (int nf = 0; nf < 4; ++nf)
                acc[nf] = __builtin_amdgcn_mfma_f32_16x16x32_bf16(af, bfr[nf], acc[nf], 0, 0, 0);
        }
        __syncthreads();
    }

    float bv[4];
#pragma unroll
    for (int nf = 0; nf < 4; ++nf) bv[nf] = b1[w * 64 + nf * 16 + rl];

    float ss0 = 0.f, ss1 = 0.f, ss2 = 0.f, ss3 = 0.f;
#pragma unroll
    for (int nf = 0; nf < 4; ++nf) {
        float v0 = fmaxf(acc[nf][0] + bv[nf], 0.f);
        float v1 = fmaxf(acc[nf][1] + bv[nf], 0.f);
        float v2 = fmaxf(acc[nf][2] + bv[nf], 0.f);
        float v3 = fmaxf(acc[nf][3] + bv[nf], 0.f);
        acc[nf][0] = v0; acc[nf][1] = v1;
        acc[nf][2] = v2; acc[nf][3] = v3;
        ss0 += v0 * v0; ss1 += v1 * v1; ss2 += v2 * v2; ss3 += v3 * v3;
    }
#pragma unroll
    for (int m = 1; m < 16; m <<= 1) {
        ss0 += __shfl_xor(ss0, m);
        ss1 += __shfl_xor(ss1, m);
        ss2 += __shfl_xor(ss2, m);
        ss3 += __shfl_xor(ss3, m);
    }
    float ssv = (rl == 0) ? ss0 : (rl == 1) ? ss1 : (rl == 2) ? ss2 : ss3;
    if (rl < 4) ssLDS[w][g * 4 + rl] = ssv;
    __syncthreads();
    if (tid < 16) {
        float t = ssLDS[0][tid] + ssLDS[1][tid] + ssLDS[2][tid] + ssLDS[3][tid];
        invLDS[tid] = (t > 0.f) ? rsqrtf(t) : 1.0f;
    }
    __syncthreads();
#pragma unroll
    for (int j = 0; j < 4; ++j) {
        const int row = g * 4 + j;
        const float inv = invLDS[row];
#pragma unroll
        for (int nf = 0; nf < 4; ++nf)
            out[(size_t)(rows0 + row) * D + w * 64 + nf * 16 + rl] = acc[nf][j] * inv;
    }
}

// ---------------------------------------------------------------------------
extern "C" void kernel_launch(void* const* d_in, const int* in_sizes, int n_in,
                              void* d_out, int out_size, void* d_ws, size_t ws_size,
                              hipStream_t stream) {
    const float* features = (const float*)d_in[0];
    const float* W0       = (const float*)d_in[1];
    const float* b0       = (const float*)d_in[2];
    const float* W1       = (const float*)d_in[3];
    const float* b1       = (const float*)d_in[4];
    const int*   nodes2   = (const int*)d_in[5];
    const int*   neigh2   = (const int*)d_in[6];
    const int*   neigh1   = (const int*)d_in[7];
    float* out = (float*)d_out;

    // workspace layout
    char* ws = (char*)d_ws;
    __bf16* Wb0 = (__bf16*)ws;                               // 256 KB
    __bf16* Wb1 = (__bf16*)(ws + 262144);                    // 256 KB
    __bf16* X0b = (__bf16*)(ws + 524288);                    // 11264*512*2 = 11.5 MB
    __bf16* h1b = (__bf16*)(ws + 524288 + 11534336);         // 11264*256*2 = 5.75 MB

    prep_kernel<<<N1 / 4, 256, 0, stream>>>(features, W0, W1, nodes2, neigh2,
                                            neigh1, Wb0, Wb1, X0b);
    gemm0_kernel<<<N1 / 32, 512, 0, stream>>>(X0b, Wb0, b0, h1b);
    layer1_kernel<<<BATCH / 16, 256, 0, stream>>>(h1b, Wb1, b1, out);
}

// Round 8
// 101.301 us; speedup vs baseline: 1.3534x; 1.1882x over previous
//
#include <hip/hip_runtime.h>
#include <math.h>

#define D 256
#define K2 512          // 2*D
#define BATCH 1024      // n2
#define N1 11264        // n1 = B*(1+10)
#define S0 25
#define S1 10

typedef __bf16 bf16x8 __attribute__((ext_vector_type(8)));
typedef __bf16 bf16x4 __attribute__((ext_vector_type(4)));
typedef float  f32x4  __attribute__((ext_vector_type(4)));

// ---------------------------------------------------------------------------
// fused_layer0 (R4 structure, gather MLP fix): per block of 32 output rows:
//   phase 1 (gather): wave w gathers rows [8w, 8w+8): ALL 25 neighbor loads
//     of a row batched into one register array (1 vmcnt wait per row instead
//     of 2) -> ~26KB in flight per wave. Self + mean -> bf16 -> LDS A-tile
//     [32][512] with XOR granule swizzle (granule ^= row&7) so the MFMA
//     fragment ds_read_b128 (16 lanes at row-stride 1KB) is conflict-free.
//   phase 2 (GEMM): 8 k-tiles of 64; B staged from fp32 W0 with inline bf16
//     convert (reg-prefetched); 16x16x32 bf16 MFMA; A resident in LDS.
//   epilogue: bias + relu + row-l2norm -> h1b (bf16).
// Fragment mapping (m89): A/B lane l: row/col=l&15, k=(l>>4)*8+i.
// C/D: col=l&15, row=(l>>4)*4+reg.
// ---------------------------------------------------------------------------
__global__ __launch_bounds__(256, 2) void fused_layer0(
        const float* __restrict__ feat, const float* __restrict__ W0,
        const float* __restrict__ b0, const int* __restrict__ nodes2,
        const int* __restrict__ neigh2, const int* __restrict__ neigh1,
        __bf16* __restrict__ h1b) {
    __shared__ __bf16 Atile[32 * 512];   // 32KB, swizzled granules of 8 bf16
    __shared__ __bf16 Bs[256 * 64];      // 32KB, tile16 layout
    __shared__ float ssLDS[4][32];
    __shared__ float invLDS[32];

    const int tid = threadIdx.x;
    const int lane = tid & 63;
    const int w = tid >> 6;
    const int rl = lane & 15;
    const int g = lane >> 4;
    const int row0 = blockIdx.x * 32;

    // ---- B prologue loads (k0 = 0), fp32, 2 float4 per slot ----
    float4 rb0[8], rb1[8];
#pragma unroll
    for (int s = 0; s < 8; ++s) {
        int i = tid + s * 256;
        int cg = i >> 7, kc = (i >> 4) & 7, lo = i & 15;
        const float* p = W0 + (size_t)(cg * 16 + lo) * K2 + kc * 8;
        rb0[s] = *(const float4*)p;
        rb1[s] = *(const float4*)(p + 4);
    }

    // ---- gather phase: wave w handles rows [8w, 8w+8), one batch per row ----
#pragma unroll 1
    for (int r = w * 8; r < w * 8 + 8; ++r) {
        const int gr = row0 + r;
        const int self_idx = (gr < BATCH) ? nodes2[gr] : neigh2[gr - BATCH];
        const int* nb = neigh1 + (size_t)gr * S0;
        int idx[S0];
#pragma unroll
        for (int j = 0; j < S0; ++j) idx[j] = nb[j];
        float4 sv = ((const float4*)(feat + (size_t)self_idx * D))[lane];
        float4 v[S0];
#pragma unroll
        for (int j = 0; j < S0; ++j)
            v[j] = ((const float4*)(feat + (size_t)idx[j] * D))[lane];
        float4 acc = make_float4(0.f, 0.f, 0.f, 0.f);
#pragma unroll
        for (int j = 0; j < S0; ++j) {
            acc.x += v[j].x; acc.y += v[j].y; acc.z += v[j].z; acc.w += v[j].w;
        }
        const float s25 = 1.0f / 25.0f;
        bf16x4 svb = { (__bf16)sv.x, (__bf16)sv.y, (__bf16)sv.z, (__bf16)sv.w };
        bf16x4 avb = { (__bf16)(acc.x * s25), (__bf16)(acc.y * s25),
                       (__bf16)(acc.z * s25), (__bf16)(acc.w * s25) };
        // self dims [4l,4l+4) -> granule l>>1 (half l&1); agg dims +256 -> +32 granules
        const int sw = r & 7;
        const int gs = (lane >> 1) ^ sw;
        const int ga = (32 + (lane >> 1)) ^ sw;
        *(bf16x4*)(Atile + (size_t)r * 512 + gs * 8 + (lane & 1) * 4) = svb;
        *(bf16x4*)(Atile + (size_t)r * 512 + ga * 8 + (lane & 1) * 4) = avb;
    }
    __syncthreads();

    // ---- GEMM phase ----
    f32x4 acc[2][4];
#pragma unroll
    for (int rf = 0; rf < 2; ++rf)
#pragma unroll
        for (int nf = 0; nf < 4; ++nf) acc[rf][nf] = (f32x4){0.f, 0.f, 0.f, 0.f};

    for (int k0 = 0; k0 < K2; k0 += 64) {
        // write Bs from prefetched fp32 regs with inline cvt (linear in tid)
#pragma unroll
        for (int s = 0; s < 8; ++s) {
            int i = tid + s * 256;
            bf16x8 bv;
            bv[0] = (__bf16)rb0[s].x; bv[1] = (__bf16)rb0[s].y;
            bv[2] = (__bf16)rb0[s].z; bv[3] = (__bf16)rb0[s].w;
            bv[4] = (__bf16)rb1[s].x; bv[5] = (__bf16)rb1[s].y;
            bv[6] = (__bf16)rb1[s].z; bv[7] = (__bf16)rb1[s].w;
            *(bf16x8*)(Bs + (size_t)i * 8) = bv;
        }
        __syncthreads();
        if (k0 + 64 < K2) {
#pragma unroll
            for (int s = 0; s < 8; ++s) {
                int i = tid + s * 256;
                int cg = i >> 7, kc = (i >> 4) & 7, lo = i & 15;
                const float* p = W0 + (size_t)(cg * 16 + lo) * K2 + (k0 + 64) + kc * 8;
                rb0[s] = *(const float4*)p;
                rb1[s] = *(const float4*)(p + 4);
            }
        }
#pragma unroll
        for (int kf = 0; kf < 2; ++kf) {
            const int kc = kf * 4 + g;
            const int gA = (k0 >> 3) + kc;  // granule index within a row
            bf16x8 af[2], bfr[4];
#pragma unroll
            for (int rf = 0; rf < 2; ++rf) {
                int row = rf * 16 + rl;
                af[rf] = *(const bf16x8*)(Atile + (size_t)row * 512 +
                                          (size_t)(gA ^ (row & 7)) * 8);
            }
#pragma unroll
            for (int nf = 0; nf < 4; ++nf)
                bfr[nf] = *(const bf16x8*)(Bs + ((size_t)((w * 4 + nf) * 8 + kc) * 16 + rl) * 8);
#pragma unroll
            for (int rf = 0; rf < 2; ++rf)
#pragma unroll
                for (int nf = 0; nf < 4; ++nf)
                    acc[rf][nf] = __builtin_amdgcn_mfma_f32_16x16x32_bf16(
                        af[rf], bfr[nf], acc[rf][nf], 0, 0, 0);
        }
        __syncthreads();
    }

    // ---- epilogue: bias + relu + row L2 norm + store bf16 ----
    float bv[4];
#pragma unroll
    for (int nf = 0; nf < 4; ++nf) bv[nf] = b0[w * 64 + nf * 16 + rl];

#pragma unroll
    for (int rf = 0; rf < 2; ++rf) {
        float ss0 = 0.f, ss1 = 0.f, ss2 = 0.f, ss3 = 0.f;
#pragma unroll
        for (int nf = 0; nf < 4; ++nf) {
            float v0 = fmaxf(acc[rf][nf][0] + bv[nf], 0.f);
            float v1 = fmaxf(acc[rf][nf][1] + bv[nf], 0.f);
            float v2 = fmaxf(acc[rf][nf][2] + bv[nf], 0.f);
            float v3 = fmaxf(acc[rf][nf][3] + bv[nf], 0.f);
            acc[rf][nf][0] = v0; acc[rf][nf][1] = v1;
            acc[rf][nf][2] = v2; acc[rf][nf][3] = v3;
            ss0 += v0 * v0; ss1 += v1 * v1; ss2 += v2 * v2; ss3 += v3 * v3;
        }
#pragma unroll
        for (int m = 1; m < 16; m <<= 1) {
            ss0 += __shfl_xor(ss0, m);
            ss1 += __shfl_xor(ss1, m);
            ss2 += __shfl_xor(ss2, m);
            ss3 += __shfl_xor(ss3, m);
        }
        float ssv = (rl == 0) ? ss0 : (rl == 1) ? ss1 : (rl == 2) ? ss2 : ss3;
        if (rl < 4) ssLDS[w][rf * 16 + g * 4 + rl] = ssv;
    }
    __syncthreads();
    if (tid < 32) {
        float t = ssLDS[0][tid] + ssLDS[1][tid] + ssLDS[2][tid] + ssLDS[3][tid];
        invLDS[tid] = (t > 0.f) ? rsqrtf(t) : 1.0f;
    }
    __syncthreads();
#pragma unroll
    for (int rf = 0; rf < 2; ++rf)
#pragma unroll
        for (int j = 0; j < 4; ++j) {
            const int row = rf * 16 + g * 4 + j;
            const float inv = invLDS[row];
#pragma unroll
            for (int nf = 0; nf < 4; ++nf)
                h1b[(size_t)(row0 + row) * D + w * 64 + nf * 16 + rl] =
                    (__bf16)(acc[rf][nf][j] * inv);
        }
}

// ---------------------------------------------------------------------------
// fused_layer1 (unchanged from R4's 101.2us build): Out[1024][256] =
// l2norm(relu(X1 @ W1^T + b1)), X1 row i = [h1[i] | mean_j h1[1024+i*10+j]]
// built on the fly in A-staging (h1 bf16). B staged from fp32 W1 with inline
// cvt + reg prefetch. RB=32.
// ---------------------------------------------------------------------------
__global__ __launch_bounds__(256, 2) void fused_layer1(
        const __bf16* __restrict__ h1, const float* __restrict__ W1,
        const float* __restrict__ b1, float* __restrict__ Out) {
    constexpr int RB = 32;
    __shared__ __bf16 As[RB * 64];
    __shared__ __bf16 Bs[256 * 64];
    __shared__ float ssLDS[4][RB];
    __shared__ float invLDS[RB];

    const int tid = threadIdx.x;
    const int row0 = blockIdx.x * RB;
    const int lane = tid & 63;
    const int w = tid >> 6;
    const int rl = lane & 15;
    const int g = lane >> 4;
    const int rg = tid >> 7, kc8 = (tid >> 4) & 7, lo = tid & 15;
    const int grow = row0 + rg * 16 + lo;

    // B prologue (k0 = 0)
    float4 rb0[8], rb1[8];
#pragma unroll
    for (int s = 0; s < 8; ++s) {
        int i = tid + s * 256;
        int cg = i >> 7, kc = (i >> 4) & 7, blo = i & 15;
        const float* p = W1 + (size_t)(cg * 16 + blo) * K2 + kc * 8;
        rb0[s] = *(const float4*)p;
        rb1[s] = *(const float4*)(p + 4);
    }

    f32x4 acc[2][4];
#pragma unroll
    for (int rf = 0; rf < 2; ++rf)
#pragma unroll
        for (int nf = 0; nf < 4; ++nf) acc[rf][nf] = (f32x4){0.f, 0.f, 0.f, 0.f};

    for (int k0 = 0; k0 < K2; k0 += 64) {
        // fused A-staging (build X1 tile on the fly)
        bf16x8 av;
        if (k0 < 256) {
            av = *(const bf16x8*)(h1 + (size_t)grow * D + k0 + kc8 * 8);
        } else {
            float f[8];
#pragma unroll
            for (int e = 0; e < 8; ++e) f[e] = 0.f;
            const __bf16* base = h1 + (size_t)(BATCH + grow * S1) * D + (k0 - 256) + kc8 * 8;
#pragma unroll
            for (int j = 0; j < S1; ++j) {
                bf16x8 vv = *(const bf16x8*)(base + (size_t)j * D);
#pragma unroll
                for (int e = 0; e < 8; ++e) f[e] += (float)vv[e];
            }
#pragma unroll
            for (int e = 0; e < 8; ++e) av[e] = (__bf16)(f[e] * 0.1f);
        }
        *(bf16x8*)(As + (size_t)tid * 8) = av;
        // B-staging from prefetched regs with cvt
#pragma unroll
        for (int s = 0; s < 8; ++s) {
            int i = tid + s * 256;
            bf16x8 bb;
            bb[0] = (__bf16)rb0[s].x; bb[1] = (__bf16)rb0[s].y;
            bb[2] = (__bf16)rb0[s].z; bb[3] = (__bf16)rb0[s].w;
            bb[4] = (__bf16)rb1[s].x; bb[5] = (__bf16)rb1[s].y;
            bb[6] = (__bf16)rb1[s].z; bb[7] = (__bf16)rb1[s].w;
            *(bf16x8*)(Bs + (size_t)i * 8) = bb;
        }
        __syncthreads();
        if (k0 + 64 < K2) {
#pragma unroll
            for (int s = 0; s < 8; ++s) {
                int i = tid + s * 256;
                int cg = i >> 7, kc = (i >> 4) & 7, blo = i & 15;
                const float* p = W1 + (size_t)(cg * 16 + blo) * K2 + (k0 + 64) + kc * 8;
                rb0[s] = *(const float4*)p;
                rb1[s] = *(const float4*)(p + 4);
            }
        }
#pragma unroll
        for (int kf = 0; kf < 2; ++kf) {
            const int kc = kf * 4 + g;
            bf16x8 af[2], bfr[4];
#pragma unroll
            for (int rf = 0; rf < 2; ++rf)
                af[rf] = *(const bf16x8*)(As + ((size_t)(rf * 8 + kc) * 16 + rl) * 8);
#pragma unroll
            for (int nf = 0; nf < 4; ++nf)
                bfr[nf] = *(const bf16x8*)(Bs + ((size_t)((w * 4 + nf) * 8 + kc) * 16 + rl) * 8);
#pragma unroll
            for (int rf = 0; rf < 2; ++rf)
#pragma unroll
                for (int nf = 0; nf < 4; ++nf)
                    acc[rf][nf] = __builtin_amdgcn_mfma_f32_16x16x32_bf16(
                        af[rf], bfr[nf], acc[rf][nf], 0, 0, 0);
        }
        __syncthreads();
    }

    float bv[4];
#pragma unroll
    for (int nf = 0; nf < 4; ++nf) bv[nf] = b1[w * 64 + nf * 16 + rl];

#pragma unroll
    for (int rf = 0; rf < 2; ++rf) {
        float ss0 = 0.f, ss1 = 0.f, ss2 = 0.f, ss3 = 0.f;
#pragma unroll
        for (int nf = 0; nf < 4; ++nf) {
            float v0 = fmaxf(acc[rf][nf][0] + bv[nf], 0.f);
            float v1 = fmaxf(acc[rf][nf][1] + bv[nf], 0.f);
            float v2 = fmaxf(acc[rf][nf][2] + bv[nf], 0.f);
            float v3 = fmaxf(acc[rf][nf][3] + bv[nf], 0.f);
            acc[rf][nf][0] = v0; acc[rf][nf][1] = v1;
            acc[rf][nf][2] = v2; acc[rf][nf][3] = v3;
            ss0 += v0 * v0; ss1 += v1 * v1; ss2 += v2 * v2; ss3 += v3 * v3;
        }
#pragma unroll
        for (int m = 1; m < 16; m <<= 1) {
            ss0 += __shfl_xor(ss0, m);
            ss1 += __shfl_xor(ss1, m);
            ss2 += __shfl_xor(ss2, m);
            ss3 += __shfl_xor(ss3, m);
        }
        float ssv = (rl == 0) ? ss0 : (rl == 1) ? ss1 : (rl == 2) ? ss2 : ss3;
        if (rl < 4) ssLDS[w][rf * 16 + g * 4 + rl] = ssv;
    }
    __syncthreads();
    if (tid < RB) {
        float t = ssLDS[0][tid] + ssLDS[1][tid] + ssLDS[2][tid] + ssLDS[3][tid];
        invLDS[tid] = (t > 0.f) ? rsqrtf(t) : 1.0f;
    }
    __syncthreads();
#pragma unroll
    for (int rf = 0; rf < 2; ++rf)
#pragma unroll
        for (int j = 0; j < 4; ++j) {
            const int row = rf * 16 + g * 4 + j;
            const float inv = invLDS[row];
#pragma unroll
            for (int nf = 0; nf < 4; ++nf)
                Out[(size_t)(row0 + row) * D + w * 64 + nf * 16 + rl] = acc[rf][nf][j] * inv;
        }
}

// ---------------------------------------------------------------------------
extern "C" void kernel_launch(void* const* d_in, const int* in_sizes, int n_in,
                              void* d_out, int out_size, void* d_ws, size_t ws_size,
                              hipStream_t stream) {
    const float* features = (const float*)d_in[0];
    const float* W0       = (const float*)d_in[1];
    const float* b0       = (const float*)d_in[2];
    const float* W1       = (const float*)d_in[3];
    const float* b1       = (const float*)d_in[4];
    const int*   nodes2   = (const int*)d_in[5];
    const int*   neigh2   = (const int*)d_in[6];
    const int*   neigh1   = (const int*)d_in[7];
    float* out = (float*)d_out;

    __bf16* h1b = (__bf16*)d_ws;   // 11264*256*2 = 5.75 MB

    fused_layer0<<<N1 / 32, 256, 0, stream>>>(features, W0, b0, nodes2, neigh2,
                                              neigh1, h1b);
    fused_layer1<<<BATCH / 32, 256, 0, stream>>>(h1b, W1, b1, out);
}

// Round 9
// 100.840 us; speedup vs baseline: 1.3596x; 1.0046x over previous
//
#include <hip/hip_runtime.h>
#include <math.h>

#define D 256
#define K2 512          // 2*D
#define BATCH 1024      // n2
#define N1 11264        // n1 = B*(1+10)
#define S0 25
#define S1 10

typedef __bf16 bf16x8 __attribute__((ext_vector_type(8)));
typedef __bf16 bf16x4 __attribute__((ext_vector_type(4)));
typedef float  f32x4  __attribute__((ext_vector_type(4)));

// ---------------------------------------------------------------------------
// fused_layer0: per block of 32 output rows:
//   phase 1 (gather): wave w gathers rows [8w, 8w+8). ALL 26 row-loads (self
//     + 25 neighbors) are issued back-to-back and PINNED before the first use
//     by __builtin_amdgcn_sched_barrier(0) - without the fence the compiler
//     re-schedules into short load/add chains (R8: VGPR stayed 104, no MLP
//     gain). With it: ~26KB in flight per wave, one vmcnt wait per row.
//     VGPR rises to ~150-190 -> still 8 waves/CU tier; LDS (64KB -> 2 blocks
//     x 4 waves) was already the occupancy binder, so TLP is unchanged.
//   phase 2 (GEMM): 8 k-tiles of 64; B staged from fp32 W0 with inline bf16
//     cvt (reg-prefetched); 16x16x32 bf16 MFMA; A resident in swizzled LDS.
//   epilogue: bias + relu + row-l2norm -> h1b (bf16).
// Fragment mapping (m89): A/B lane l: row/col=l&15, k=(l>>4)*8+i.
// C/D: col=l&15, row=(l>>4)*4+reg.
// ---------------------------------------------------------------------------
__global__ __launch_bounds__(256, 2) void fused_layer0(
        const float* __restrict__ feat, const float* __restrict__ W0,
        const float* __restrict__ b0, const int* __restrict__ nodes2,
        const int* __restrict__ neigh2, const int* __restrict__ neigh1,
        __bf16* __restrict__ h1b) {
    __shared__ __bf16 Atile[32 * 512];   // 32KB, swizzled granules of 8 bf16
    __shared__ __bf16 Bs[256 * 64];      // 32KB, tile16 layout
    __shared__ float ssLDS[4][32];
    __shared__ float invLDS[32];

    const int tid = threadIdx.x;
    const int lane = tid & 63;
    const int w = tid >> 6;
    const int rl = lane & 15;
    const int g = lane >> 4;
    const int row0 = blockIdx.x * 32;

    // ---- B prologue loads (k0 = 0), fp32, 2 float4 per slot ----
    float4 rb0[8], rb1[8];
#pragma unroll
    for (int s = 0; s < 8; ++s) {
        int i = tid + s * 256;
        int cg = i >> 7, kc = (i >> 4) & 7, lo = i & 15;
        const float* p = W0 + (size_t)(cg * 16 + lo) * K2 + kc * 8;
        rb0[s] = *(const float4*)p;
        rb1[s] = *(const float4*)(p + 4);
    }

    // ---- gather phase: wave w handles rows [8w, 8w+8), 26 loads in flight ----
#pragma unroll 1
    for (int r = w * 8; r < w * 8 + 8; ++r) {
        const int gr = row0 + r;
        const int self_idx = (gr < BATCH) ? nodes2[gr] : neigh2[gr - BATCH];
        const int* nb = neigh1 + (size_t)gr * S0;
        int idx[S0];
#pragma unroll
        for (int j = 0; j < S0; ++j) idx[j] = nb[j];
        // issue all 26 row loads back-to-back
        float4 sv = ((const float4*)(feat + (size_t)self_idx * D))[lane];
        float4 v[S0];
#pragma unroll
        for (int j = 0; j < S0; ++j)
            v[j] = ((const float4*)(feat + (size_t)idx[j] * D))[lane];
        // compile-time fence: nothing may cross; forces all loads to stay
        // issued before the first consume (25 distinct dest regs, vmcnt(24)
        // at first add instead of 8 serial load/add chains).
        __builtin_amdgcn_sched_barrier(0);
        float4 acc = make_float4(0.f, 0.f, 0.f, 0.f);
#pragma unroll
        for (int j = 0; j < S0; ++j) {
            acc.x += v[j].x; acc.y += v[j].y; acc.z += v[j].z; acc.w += v[j].w;
        }
        const float s25 = 1.0f / 25.0f;
        bf16x4 svb = { (__bf16)sv.x, (__bf16)sv.y, (__bf16)sv.z, (__bf16)sv.w };
        bf16x4 avb = { (__bf16)(acc.x * s25), (__bf16)(acc.y * s25),
                       (__bf16)(acc.z * s25), (__bf16)(acc.w * s25) };
        // self dims [4l,4l+4) -> granule l>>1 (half l&1); agg dims +256 -> +32 granules
        const int sw = r & 7;
        const int gs = (lane >> 1) ^ sw;
        const int ga = (32 + (lane >> 1)) ^ sw;
        *(bf16x4*)(Atile + (size_t)r * 512 + gs * 8 + (lane & 1) * 4) = svb;
        *(bf16x4*)(Atile + (size_t)r * 512 + ga * 8 + (lane & 1) * 4) = avb;
    }
    __syncthreads();

    // ---- GEMM phase ----
    f32x4 acc[2][4];
#pragma unroll
    for (int rf = 0; rf < 2; ++rf)
#pragma unroll
        for (int nf = 0; nf < 4; ++nf) acc[rf][nf] = (f32x4){0.f, 0.f, 0.f, 0.f};

    for (int k0 = 0; k0 < K2; k0 += 64) {
        // write Bs from prefetched fp32 regs with inline cvt (linear in tid)
#pragma unroll
        for (int s = 0; s < 8; ++s) {
            int i = tid + s * 256;
            bf16x8 bv;
            bv[0] = (__bf16)rb0[s].x; bv[1] = (__bf16)rb0[s].y;
            bv[2] = (__bf16)rb0[s].z; bv[3] = (__bf16)rb0[s].w;
            bv[4] = (__bf16)rb1[s].x; bv[5] = (__bf16)rb1[s].y;
            bv[6] = (__bf16)rb1[s].z; bv[7] = (__bf16)rb1[s].w;
            *(bf16x8*)(Bs + (size_t)i * 8) = bv;
        }
        __syncthreads();
        if (k0 + 64 < K2) {
#pragma unroll
            for (int s = 0; s < 8; ++s) {
                int i = tid + s * 256;
                int cg = i >> 7, kc = (i >> 4) & 7, lo = i & 15;
                const float* p = W0 + (size_t)(cg * 16 + lo) * K2 + (k0 + 64) + kc * 8;
                rb0[s] = *(const float4*)p;
                rb1[s] = *(const float4*)(p + 4);
            }
        }
#pragma unroll
        for (int kf = 0; kf < 2; ++kf) {
            const int kc = kf * 4 + g;
            const int gA = (k0 >> 3) + kc;  // granule index within a row
            bf16x8 af[2], bfr[4];
#pragma unroll
            for (int rf = 0; rf < 2; ++rf) {
                int row = rf * 16 + rl;
                af[rf] = *(const bf16x8*)(Atile + (size_t)row * 512 +
                                          (size_t)(gA ^ (row & 7)) * 8);
            }
#pragma unroll
            for (int nf = 0; nf < 4; ++nf)
                bfr[nf] = *(const bf16x8*)(Bs + ((size_t)((w * 4 + nf) * 8 + kc) * 16 + rl) * 8);
#pragma unroll
            for (int rf = 0; rf < 2; ++rf)
#pragma unroll
                for (int nf = 0; nf < 4; ++nf)
                    acc[rf][nf] = __builtin_amdgcn_mfma_f32_16x16x32_bf16(
                        af[rf], bfr[nf], acc[rf][nf], 0, 0, 0);
        }
        __syncthreads();
    }

    // ---- epilogue: bias + relu + row L2 norm + store bf16 ----
    float bv[4];
#pragma unroll
    for (int nf = 0; nf < 4; ++nf) bv[nf] = b0[w * 64 + nf * 16 + rl];

#pragma unroll
    for (int rf = 0; rf < 2; ++rf) {
        float ss0 = 0.f, ss1 = 0.f, ss2 = 0.f, ss3 = 0.f;
#pragma unroll
        for (int nf = 0; nf < 4; ++nf) {
            float v0 = fmaxf(acc[rf][nf][0] + bv[nf], 0.f);
            float v1 = fmaxf(acc[rf][nf][1] + bv[nf], 0.f);
            float v2 = fmaxf(acc[rf][nf][2] + bv[nf], 0.f);
            float v3 = fmaxf(acc[rf][nf][3] + bv[nf], 0.f);
            acc[rf][nf][0] = v0; acc[rf][nf][1] = v1;
            acc[rf][nf][2] = v2; acc[rf][nf][3] = v3;
            ss0 += v0 * v0; ss1 += v1 * v1; ss2 += v2 * v2; ss3 += v3 * v3;
        }
#pragma unroll
        for (int m = 1; m < 16; m <<= 1) {
            ss0 += __shfl_xor(ss0, m);
            ss1 += __shfl_xor(ss1, m);
            ss2 += __shfl_xor(ss2, m);
            ss3 += __shfl_xor(ss3, m);
        }
        float ssv = (rl == 0) ? ss0 : (rl == 1) ? ss1 : (rl == 2) ? ss2 : ss3;
        if (rl < 4) ssLDS[w][rf * 16 + g * 4 + rl] = ssv;
    }
    __syncthreads();
    if (tid < 32) {
        float t = ssLDS[0][tid] + ssLDS[1][tid] + ssLDS[2][tid] + ssLDS[3][tid];
        invLDS[tid] = (t > 0.f) ? rsqrtf(t) : 1.0f;
    }
    __syncthreads();
#pragma unroll
    for (int rf = 0; rf < 2; ++rf)
#pragma unroll
        for (int j = 0; j < 4; ++j) {
            const int row = rf * 16 + g * 4 + j;
            const float inv = invLDS[row];
#pragma unroll
            for (int nf = 0; nf < 4; ++nf)
                h1b[(size_t)(row0 + row) * D + w * 64 + nf * 16 + rl] =
                    (__bf16)(acc[rf][nf][j] * inv);
        }
}

// ---------------------------------------------------------------------------
// fused_layer1 (unchanged, ~9-10us): Out[1024][256] = l2norm(relu(X1 @ W1^T
// + b1)), X1 row i = [h1[i] | mean_j h1[1024+i*10+j]] built on the fly in
// A-staging (h1 bf16). B staged from fp32 W1 with inline cvt + reg prefetch.
// ---------------------------------------------------------------------------
__global__ __launch_bounds__(256, 2) void fused_layer1(
        const __bf16* __restrict__ h1, const float* __restrict__ W1,
        const float* __restrict__ b1, float* __restrict__ Out) {
    constexpr int RB = 32;
    __shared__ __bf16 As[RB * 64];
    __shared__ __bf16 Bs[256 * 64];
    __shared__ float ssLDS[4][RB];
    __shared__ float invLDS[RB];

    const int tid = threadIdx.x;
    const int row0 = blockIdx.x * RB;
    const int lane = tid & 63;
    const int w = tid >> 6;
    const int rl = lane & 15;
    const int g = lane >> 4;
    const int rg = tid >> 7, kc8 = (tid >> 4) & 7, lo = tid & 15;
    const int grow = row0 + rg * 16 + lo;

    // B prologue (k0 = 0)
    float4 rb0[8], rb1[8];
#pragma unroll
    for (int s = 0; s < 8; ++s) {
        int i = tid + s * 256;
        int cg = i >> 7, kc = (i >> 4) & 7, blo = i & 15;
        const float* p = W1 + (size_t)(cg * 16 + blo) * K2 + kc * 8;
        rb0[s] = *(const float4*)p;
        rb1[s] = *(const float4*)(p + 4);
    }

    f32x4 acc[2][4];
#pragma unroll
    for (int rf = 0; rf < 2; ++rf)
#pragma unroll
        for (int nf = 0; nf < 4; ++nf) acc[rf][nf] = (f32x4){0.f, 0.f, 0.f, 0.f};

    for (int k0 = 0; k0 < K2; k0 += 64) {
        // fused A-staging (build X1 tile on the fly)
        bf16x8 av;
        if (k0 < 256) {
            av = *(const bf16x8*)(h1 + (size_t)grow * D + k0 + kc8 * 8);
        } else {
            float f[8];
#pragma unroll
            for (int e = 0; e < 8; ++e) f[e] = 0.f;
            const __bf16* base = h1 + (size_t)(BATCH + grow * S1) * D + (k0 - 256) + kc8 * 8;
#pragma unroll
            for (int j = 0; j < S1; ++j) {
                bf16x8 vv = *(const bf16x8*)(base + (size_t)j * D);
#pragma unroll
                for (int e = 0; e < 8; ++e) f[e] += (float)vv[e];
            }
#pragma unroll
            for (int e = 0; e < 8; ++e) av[e] = (__bf16)(f[e] * 0.1f);
        }
        *(bf16x8*)(As + (size_t)tid * 8) = av;
        // B-staging from prefetched regs with cvt
#pragma unroll
        for (int s = 0; s < 8; ++s) {
            int i = tid + s * 256;
            bf16x8 bb;
            bb[0] = (__bf16)rb0[s].x; bb[1] = (__bf16)rb0[s].y;
            bb[2] = (__bf16)rb0[s].z; bb[3] = (__bf16)rb0[s].w;
            bb[4] = (__bf16)rb1[s].x; bb[5] = (__bf16)rb1[s].y;
            bb[6] = (__bf16)rb1[s].z; bb[7] = (__bf16)rb1[s].w;
            *(bf16x8*)(Bs + (size_t)i * 8) = bb;
        }
        __syncthreads();
        if (k0 + 64 < K2) {
#pragma unroll
            for (int s = 0; s < 8; ++s) {
                int i = tid + s * 256;
                int cg = i >> 7, kc = (i >> 4) & 7, blo = i & 15;
                const float* p = W1 + (size_t)(cg * 16 + blo) * K2 + (k0 + 64) + kc * 8;
                rb0[s] = *(const float4*)p;
                rb1[s] = *(const float4*)(p + 4);
            }
        }
#pragma unroll
        for (int kf = 0; kf < 2; ++kf) {
            const int kc = kf * 4 + g;
            bf16x8 af[2], bfr[4];
#pragma unroll
            for (int rf = 0; rf < 2; ++rf)
                af[rf] = *(const bf16x8*)(As + ((size_t)(rf * 8 + kc) * 16 + rl) * 8);
#pragma unroll
            for (int nf = 0; nf < 4; ++nf)
                bfr[nf] = *(const bf16x8*)(Bs + ((size_t)((w * 4 + nf) * 8 + kc) * 16 + rl) * 8);
#pragma unroll
            for (int rf = 0; rf < 2; ++rf)
#pragma unroll
                for (int nf = 0; nf < 4; ++nf)
                    acc[rf][nf] = __builtin_amdgcn_mfma_f32_16x16x32_bf16(
                        af[rf], bfr[nf], acc[rf][nf], 0, 0, 0);
        }
        __syncthreads();
    }

    float bv[4];
#pragma unroll
    for (int nf = 0; nf < 4; ++nf) bv[nf] = b1[w * 64 + nf * 16 + rl];

#pragma unroll
    for (int rf = 0; rf < 2; ++rf) {
        float ss0 = 0.f, ss1 = 0.f, ss2 = 0.f, ss3 = 0.f;
#pragma unroll
        for (int nf = 0; nf < 4; ++nf) {
            float v0 = fmaxf(acc[rf][nf][0] + bv[nf], 0.f);
            float v1 = fmaxf(acc[rf][nf][1] + bv[nf], 0.f);
            float v2 = fmaxf(acc[rf][nf][2] + bv[nf], 0.f);
            float v3 = fmaxf(acc[rf][nf][3] + bv[nf], 0.f);
            acc[rf][nf][0] = v0; acc[rf][nf][1] = v1;
            acc[rf][nf][2] = v2; acc[rf][nf][3] = v3;
            ss0 += v0 * v0; ss1 += v1 * v1; ss2 += v2 * v2; ss3 += v3 * v3;
        }
#pragma unroll
        for (int m = 1; m < 16; m <<= 1) {
            ss0 += __shfl_xor(ss0, m);
            ss1 += __shfl_xor(ss1, m);
            ss2 += __shfl_xor(ss2, m);
            ss3 += __shfl_xor(ss3, m);
        }
        float ssv = (rl == 0) ? ss0 : (rl == 1) ? ss1 : (rl == 2) ? ss2 : ss3;
        if (rl < 4) ssLDS[w][rf * 16 + g * 4 + rl] = ssv;
    }
    __syncthreads();
    if (tid < RB) {
        float t = ssLDS[0][tid] + ssLDS[1][tid] + ssLDS[2][tid] + ssLDS[3][tid];
        invLDS[tid] = (t > 0.f) ? rsqrtf(t) : 1.0f;
    }
    __syncthreads();
#pragma unroll
    for (int rf = 0; rf < 2; ++rf)
#pragma unroll
        for (int j = 0; j < 4; ++j) {
            const int row = rf * 16 + g * 4 + j;
            const float inv = invLDS[row];
#pragma unroll
            for (int nf = 0; nf < 4; ++nf)
                Out[(size_t)(row0 + row) * D + w * 64 + nf * 16 + rl] = acc[rf][nf][j] * inv;
        }
}

// ---------------------------------------------------------------------------
extern "C" void kernel_launch(void* const* d_in, const int* in_sizes, int n_in,
                              void* d_out, int out_size, void* d_ws, size_t ws_size,
                              hipStream_t stream) {
    const float* features = (const float*)d_in[0];
    const float* W0       = (const float*)d_in[1];
    const float* b0       = (const float*)d_in[2];
    const float* W1       = (const float*)d_in[3];
    const float* b1       = (const float*)d_in[4];
    const int*   nodes2   = (const int*)d_in[5];
    const int*   neigh2   = (const int*)d_in[6];
    const int*   neigh1   = (const int*)d_in[7];
    float* out = (float*)d_out;

    __bf16* h1b = (__bf16*)d_ws;   // 11264*256*2 = 5.75 MB

    fused_layer0<<<N1 / 32, 256, 0, stream>>>(features, W0, b0, nodes2, neigh2,
                                              neigh1, h1b);
    fused_layer1<<<BATCH / 32, 256, 0, stream>>>(h1b, W1, b1, out);
}